// Round 13
// baseline (140.906 us; speedup 1.0000x reference)
//
#include <hip/hip_runtime.h>
#include <hip/hip_fp16.h>

// MLPKANlayer: out[b][o] = sum_i g_n(x[b,i]), n = i*128+o,
//   g_n(x) = y_n(x)*ss_n + x*rs_n  (1->5->5->1 SiLU MLP). f32 in/out.
//
// R13 = R12's uniform-k coalesced scan, saturated:
//   table tbl[i][k][o] (half2 value,slope): segment index k depends only on
//   (b,i); wave = (b, o-half, i-half) -> k uniform, 64 lanes read consecutive
//   half2 = one coalesced 256-B load; 4 B per eval is the design's
//   irreducible traffic (134 MB L2-class).
//   main: 8192 waves (32/CU = 100% occ), x preloaded to SGPRs before the
//   loop, only the table load in-loop; i-half pairs reduce via 1 KB LDS.
//   build: block=(i,o-half) -> 256 blocks (all CUs), padded LDS, coalesced
//   writes. Tails extrapolate (k clamped to [0,126], fraction free).
// Harness floor ~63us (256 MiB d_ws re-poison + restores) is fixed.

constexpr int IN_SZ = 128, OUT_SZ = 128, BATCH = 2048, NSUB = IN_SZ * OUT_SZ;
constexpr int KNOTS = 128, NSEG = KNOTS - 1;
constexpr float XMIN = -5.0f, XRANGE = 10.0f;
constexpr float STEP = XRANGE / (float)NSEG;
constexpr float INVH = (float)NSEG / XRANGE;   // 12.7
constexpr float UOFF = -XMIN * INVH;           // 63.5

__device__ __forceinline__ float silu_f(float z) {
  float t = __builtin_amdgcn_exp2f(z * -1.44269504088896f);   // exp(-z)
  return z * __builtin_amdgcn_rcpf(1.0f + t);
}

// ---- k1: build tbl[i][k][o] = half2(g(x_k), g(x_{k+1})-g(x_k)) -------------
// Block = (i, o-half): 256 blocks x 1024 thr. Lanes over k; o wave-uniform
// -> weights are s_loads. v padded (stride 65) -> 2-way LDS access = free.
__global__ __launch_bounds__(1024) void build_ikol(
    const float* __restrict__ w0, const float* __restrict__ b0,
    const float* __restrict__ w1, const float* __restrict__ b1,
    const float* __restrict__ w2, const float* __restrict__ b2,
    const float* __restrict__ ss, const float* __restrict__ rs,
    __half2* __restrict__ tbl) {
  __shared__ float v[KNOTS * 65];               // 128 k x 64 o, padded
  const int tid = threadIdx.x;
  const int i   = blockIdx.x >> 1;
  const int oh  = blockIdx.x & 1;               // o-half
  const int k   = tid & (KNOTS - 1);            // per-lane knot
  const int og  = __builtin_amdgcn_readfirstlane(tid >> 7);   // 0..7 uniform

  const float xk = XMIN + (float)k * STEP;

#pragma unroll 1
  for (int j = 0; j < 8; ++j) {
    const int ol = og + 8 * j;                  // wave-uniform, 0..63
    const int n  = i * OUT_SZ + oh * 64 + ol;   // scalar -> weights s_load
    float h1[5], h2[5];
#pragma unroll
    for (int jj = 0; jj < 5; ++jj)
      h1[jj] = silu_f(fmaf(w0[n * 5 + jj], xk, b0[n * 5 + jj]));
#pragma unroll
    for (int jj = 0; jj < 5; ++jj) {
      float z = b1[n * 5 + jj];
#pragma unroll
      for (int kk = 0; kk < 5; ++kk)
        z = fmaf(w1[n * 25 + jj * 5 + kk], h1[kk], z);
      h2[jj] = silu_f(z);
    }
    float y = b2[n];
#pragma unroll
    for (int kk = 0; kk < 5; ++kk) y = fmaf(w2[n * 5 + kk], h2[kk], y);
    v[k * 65 + ol] = fmaf(y, ss[n], xk * rs[n]);
  }
  __syncthreads();

  // write coalesced: 8192 entries = 128 k x 64 o; consecutive tid -> consec o
#pragma unroll
  for (int s = 0; s < 8; ++s) {
    const int idx = tid + 1024 * s;
    const int kk = idx >> 6, ol = idx & 63;
    const float a  = v[kk * 65 + ol];
    const float sl = (kk < NSEG) ? (v[(kk + 1) * 65 + ol] - a) : 0.0f;
    tbl[((size_t)i << 14) + (kk << 7) + oh * 64 + ol] = __floats2half2_rn(a, sl);
  }
}

// ---- k2: main — 8192 waves, SGPR x, coalesced table reads ------------------
__global__ __launch_bounds__(512) void mlp_scan2(
    const float* __restrict__ x, const __half2* __restrict__ tbl,
    float* __restrict__ out) {
  __shared__ float red[2][128];                 // [b-local][od]

  const int tid  = threadIdx.x;
  const int wv   = __builtin_amdgcn_readfirstlane(tid >> 6);  // 0..7 uniform
  const int lane = tid & 63;
  const int ih = wv & 1, oh = (wv >> 1) & 1, bl = wv >> 2;
  const int b  = blockIdx.x * 2 + bl;           // wave-uniform batch row
  const int od = oh * 64 + lane;

  const float* __restrict__ xr = x + (size_t)b * IN_SZ + ih * 64;
  const __half2* __restrict__ tb = tbl + (((size_t)ih << 6) << 14) + od;

  // preload 64 uniform x values -> SGPRs (s_load_dwordx16 x4)
  float xs[64];
#pragma unroll
  for (int i = 0; i < 64; ++i) xs[i] = xr[i];

  float acc0 = 0.0f, acc1 = 0.0f;
#pragma unroll 16
  for (int i = 0; i < 64; ++i) {
    float u  = fmaf(xs[i], INVH, UOFF);
    float fi = __builtin_amdgcn_fmed3f(floorf(u), 0.0f, (float)(NSEG - 1));
    float f  = u - fi;                          // unclamped -> extrapolate
    int k    = (int)fi;                         // wave-uniform
    __half2 h = tb[(size_t)((i << 7) + k) << 7];   // coalesced 256 B
    float t = fmaf(__half2float(__high2half(h)), f,
                   __half2float(__low2half(h)));
    if (i & 1) acc1 += t; else acc0 += t;
  }
  float acc = acc0 + acc1;

  if (ih) red[bl][od] = acc;
  __syncthreads();
  if (!ih) out[(size_t)b * OUT_SZ + od] = acc + red[bl][od];
}

// ---- fallback (ws too small): exact raw-array kernel -----------------------
__global__ __launch_bounds__(512) void mlp_raw(
    const float* __restrict__ x,
    const float* __restrict__ w0, const float* __restrict__ b0,
    const float* __restrict__ w1, const float* __restrict__ b1,
    const float* __restrict__ w2, const float* __restrict__ b2,
    const float* __restrict__ ss, const float* __restrict__ rs,
    float* __restrict__ out) {
  __shared__ float red[256];
  const int tid  = threadIdx.x;
  const int wave = __builtin_amdgcn_readfirstlane(tid) >> 6;
  const int lane = tid & 63;
  const int half = wave >> 2;
  const int sub  = wave & 3;
  const int o     = blockIdx.x & (OUT_SZ - 1);
  const int chunk = blockIdx.x >> 7;
  const int b     = chunk * 256 + sub * 64 + lane;
  const int i0    = half * 64;
  const float4* __restrict__ xrow = (const float4*)(x + (size_t)b * IN_SZ + i0);
  float acc = 0.0f;
#pragma unroll 1
  for (int c = 0; c < 16; ++c) {
    float4 xv = xrow[c];
    float xs[4] = { xv.x, xv.y, xv.z, xv.w };
#pragma unroll
    for (int r = 0; r < 4; ++r) {
      int n = (i0 + c * 4 + r) * OUT_SZ + o;
      float h1[5], h2[5];
#pragma unroll
      for (int j = 0; j < 5; ++j)
        h1[j] = silu_f(fmaf(w0[n * 5 + j], xs[r], b0[n * 5 + j]));
#pragma unroll
      for (int j = 0; j < 5; ++j) {
        float z = b1[n * 5 + j];
#pragma unroll
        for (int k = 0; k < 5; ++k) z = fmaf(w1[n * 25 + j * 5 + k], h1[k], z);
        h2[j] = silu_f(z);
      }
      float y = b2[n];
#pragma unroll
      for (int k = 0; k < 5; ++k) y = fmaf(w2[n * 5 + k], h2[k], y);
      acc += fmaf(y, ss[n], xs[r] * rs[n]);
    }
  }
  if (half) red[sub * 64 + lane] = acc;
  __syncthreads();
  if (!half) out[(size_t)b * OUT_SZ + o] = acc + red[sub * 64 + lane];
}

extern "C" void kernel_launch(void* const* d_in, const int* in_sizes, int n_in,
                              void* d_out, int out_size, void* d_ws, size_t ws_size,
                              hipStream_t stream) {
  const float* x  = (const float*)d_in[0];
  const float* w0 = (const float*)d_in[1];
  const float* b0 = (const float*)d_in[2];
  const float* w1 = (const float*)d_in[3];
  const float* b1 = (const float*)d_in[4];
  const float* w2 = (const float*)d_in[5];
  const float* b2 = (const float*)d_in[6];
  const float* ss = (const float*)d_in[7];
  const float* rs = (const float*)d_in[8];

  const size_t TBL_BYTES = (size_t)NSUB * KNOTS * sizeof(__half2);  // 8 MiB

  if (ws_size >= TBL_BYTES) {
    __half2* tbl = (__half2*)d_ws;
    build_ikol<<<dim3(2 * IN_SZ), dim3(1024), 0, stream>>>(
        w0, b0, w1, b1, w2, b2, ss, rs, tbl);
    mlp_scan2<<<dim3(BATCH / 2), dim3(512), 0, stream>>>(
        x, tbl, (float*)d_out);
  } else {
    mlp_raw<<<dim3(OUT_SZ * (BATCH / 256)), dim3(512), 0, stream>>>(
        x, w0, b0, w1, b1, w2, b2, ss, rs, (float*)d_out);
  }
}

// Round 14
// 95.636 us; speedup vs baseline: 1.4734x; 1.4734x over previous
//
#include <hip/hip_runtime.h>
#include <hip/hip_fp16.h>

// MLPKANlayer: out[b][o] = sum_i g_n(x[b,i]), n = i*128+o,
//   g_n(x) = y_n(x)*ss_n + x*rs_n  (1->5->5->1 SiLU MLP). f32 in/out.
//
// R14 = R11 (best: LDS-staged PW-linear table) + occupancy fix:
//   96 segments over [-4.5,4.5] -> o-slice table = 128 i x 96 seg x 4 B
//   = 48 KiB LDS -> 3 blocks/CU (24 waves, was 2/16 at 64 KiB). Error
//   h^2-scaled: ~0.0056 vs 0.0225 threshold. Slot permutation dropped
//   (R9: conflicts 1.75M cyc = negligible). Tails extrapolate linearly.
// R13 lesson: table traffic must stay in LDS — global scan cost 222 MB
// HBM/launch (poison-dirtied caches). Harness floor ~63 us is fixed.

constexpr int IN_SZ = 128, OUT_SZ = 128, BATCH = 2048, NSUB = IN_SZ * OUT_SZ;
constexpr int NSEG = 96;                     // segments; 97 knot values
constexpr float XMIN = -4.5f, XRANGE = 9.0f;
constexpr float STEP = XRANGE / (float)NSEG;
constexpr float INVH = (float)NSEG / XRANGE;   // 10.6667
constexpr float UOFF = -XMIN * INVH;           // 48

__device__ __forceinline__ float silu_f(float z) {
  float t = __builtin_amdgcn_exp2f(z * -1.44269504088896f);   // exp(-z)
  return z * __builtin_amdgcn_rcpf(1.0f + t);
}

// ---- k1 prep: build table (blocks < 8192) + transpose x (blocks >= 8192) ---
// Build: 2 subnets x 128 lanes (k = 0..96 active); subnet wave-uniform ->
// weights are s_loads. tbl[(o*128+i)*96 + k] = half2(g(x_k), g(x_{k+1})-g(x_k))
__global__ __launch_bounds__(256) void prep(
    const float* __restrict__ x,
    const float* __restrict__ w0, const float* __restrict__ b0,
    const float* __restrict__ w1, const float* __restrict__ b1,
    const float* __restrict__ w2, const float* __restrict__ b2,
    const float* __restrict__ ss, const float* __restrict__ rs,
    __half2* __restrict__ tbl, float* __restrict__ xT) {
  __shared__ float smem[64 * 65];
  const int tid = threadIdx.x;
  const int blk = blockIdx.x;

  if (blk < NSUB / 2) {
    float (*gv)[128] = (float (*)[128])smem;
    const int sl = __builtin_amdgcn_readfirstlane(tid >> 7);  // 0..1 uniform
    const int k  = tid & 127;
    const int n  = blk * 2 + sl;

    if (k <= NSEG) {
      const float xk = XMIN + (float)k * STEP;
      float h1[5], h2[5];
#pragma unroll
      for (int j = 0; j < 5; ++j)
        h1[j] = silu_f(fmaf(w0[n * 5 + j], xk, b0[n * 5 + j]));
#pragma unroll
      for (int j = 0; j < 5; ++j) {
        float z = b1[n * 5 + j];
#pragma unroll
        for (int kk = 0; kk < 5; ++kk)
          z = fmaf(w1[n * 25 + j * 5 + kk], h1[kk], z);
        h2[j] = silu_f(z);
      }
      float y = b2[n];
#pragma unroll
      for (int kk = 0; kk < 5; ++kk) y = fmaf(w2[n * 5 + kk], h2[kk], y);
      gv[sl][k] = fmaf(y, ss[n], xk * rs[n]);
    }
    __syncthreads();
    if (k < NSEG) {
      float a = gv[sl][k];
      float s = gv[sl][k + 1] - a;
      int o = n & (OUT_SZ - 1), i = n >> 7;
      tbl[(size_t)(o * IN_SZ + i) * NSEG + k] = __floats2half2_rn(a, s);
    }
  } else {
    // transpose x -> xT[i][b], 64x64 LDS tile
    float (*tile)[65] = (float (*)[65])smem;
    const int t   = blk - NSUB / 2;              // 0..63
    const int b0t = (t & 31) * 64;
    const int i0  = (t >> 5) * 64;
    const int l = tid & 63, w = tid >> 6;        // w = 0..3
#pragma unroll
    for (int r = 0; r < 16; ++r) {
      int row = w + 4 * r;
      tile[row][l] = x[(size_t)(b0t + row) * IN_SZ + i0 + l];
    }
    __syncthreads();
#pragma unroll
    for (int r = 0; r < 16; ++r) {
      int row = w + 4 * r;
      xT[(size_t)(i0 + row) * BATCH + b0t + l] = tile[l][row];
    }
  }
}

// ---- k2 main: block = (o, 512-row chunk); 48 KiB LDS table; 1 row/thread ---
__global__ __launch_bounds__(512) void mlp_tbl_lds(
    const float* __restrict__ xT, const __half2* __restrict__ tbl,
    float* __restrict__ out) {
  __shared__ __half2 ts[IN_SZ * NSEG];   // 48 KiB -> 3 blocks/CU

  const int tid   = threadIdx.x;
  const int o     = blockIdx.x & (OUT_SZ - 1);   // same-o -> same XCD
  const int chunk = blockIdx.x >> 7;             // 0..3

  // stage o-slice: 48 KiB = 3072 uint4, 6 per thread, coalesced
  {
    const uint4* __restrict__ s4 =
        (const uint4*)(tbl + (size_t)o * IN_SZ * NSEG);
    uint4* d4 = (uint4*)ts;
#pragma unroll
    for (int r = 0; r < 6; ++r) d4[tid + 512 * r] = s4[tid + 512 * r];
  }
  __syncthreads();

  const int row = chunk * 512 + tid;             // batch row

  float acc0 = 0.0f, acc1 = 0.0f, acc2 = 0.0f, acc3 = 0.0f;
#pragma unroll 8
  for (int i = 0; i < IN_SZ; ++i) {
    float xv = xT[((size_t)i << 11) + row];      // lane-contiguous, coalesced
    float u  = fmaf(xv, INVH, UOFF);
    float fi = __builtin_amdgcn_fmed3f(floorf(u), 0.0f, (float)(NSEG - 1));
    float f  = u - fi;                           // unclamped -> extrapolate
    __half2 h = ts[i * NSEG + (int)fi];
    float lo = __half2float(__low2half(h));
    float hi = __half2float(__high2half(h));
    float t  = fmaf(hi, f, lo);
    if ((i & 3) == 0) acc0 += t;
    else if ((i & 3) == 1) acc1 += t;
    else if ((i & 3) == 2) acc2 += t;
    else acc3 += t;
  }
  out[(size_t)row * OUT_SZ + o] = (acc0 + acc1) + (acc2 + acc3);
}

// ---- fallback (ws too small): exact raw-array kernel -----------------------
__global__ __launch_bounds__(512) void mlp_raw(
    const float* __restrict__ x,
    const float* __restrict__ w0, const float* __restrict__ b0,
    const float* __restrict__ w1, const float* __restrict__ b1,
    const float* __restrict__ w2, const float* __restrict__ b2,
    const float* __restrict__ ss, const float* __restrict__ rs,
    float* __restrict__ out) {
  __shared__ float red[256];
  const int tid  = threadIdx.x;
  const int wave = __builtin_amdgcn_readfirstlane(tid) >> 6;
  const int lane = tid & 63;
  const int half = wave >> 2;
  const int sub  = wave & 3;
  const int o     = blockIdx.x & (OUT_SZ - 1);
  const int chunk = blockIdx.x >> 7;
  const int b     = chunk * 256 + sub * 64 + lane;
  const int i0    = half * 64;
  const float4* __restrict__ xrow = (const float4*)(x + (size_t)b * IN_SZ + i0);
  float acc = 0.0f;
#pragma unroll 1
  for (int c = 0; c < 16; ++c) {
    float4 xv = xrow[c];
    float xs[4] = { xv.x, xv.y, xv.z, xv.w };
#pragma unroll
    for (int r = 0; r < 4; ++r) {
      int n = (i0 + c * 4 + r) * OUT_SZ + o;
      float h1[5], h2[5];
#pragma unroll
      for (int j = 0; j < 5; ++j)
        h1[j] = silu_f(fmaf(w0[n * 5 + j], xs[r], b0[n * 5 + j]));
#pragma unroll
      for (int j = 0; j < 5; ++j) {
        float z = b1[n * 5 + j];
#pragma unroll
        for (int k = 0; k < 5; ++k) z = fmaf(w1[n * 25 + j * 5 + k], h1[k], z);
        h2[j] = silu_f(z);
      }
      float y = b2[n];
#pragma unroll
      for (int k = 0; k < 5; ++k) y = fmaf(w2[n * 5 + k], h2[k], y);
      acc += fmaf(y, ss[n], xs[r] * rs[n]);
    }
  }
  if (half) red[sub * 64 + lane] = acc;
  __syncthreads();
  if (!half) out[(size_t)b * OUT_SZ + o] = acc + red[sub * 64 + lane];
}

extern "C" void kernel_launch(void* const* d_in, const int* in_sizes, int n_in,
                              void* d_out, int out_size, void* d_ws, size_t ws_size,
                              hipStream_t stream) {
  const float* x  = (const float*)d_in[0];
  const float* w0 = (const float*)d_in[1];
  const float* b0 = (const float*)d_in[2];
  const float* w1 = (const float*)d_in[3];
  const float* b1 = (const float*)d_in[4];
  const float* w2 = (const float*)d_in[5];
  const float* b2 = (const float*)d_in[6];
  const float* ss = (const float*)d_in[7];
  const float* rs = (const float*)d_in[8];

  const size_t TBL_BYTES = (size_t)NSUB * NSEG * sizeof(__half2);  // 6 MiB
  const size_t XT_BYTES  = (size_t)IN_SZ * BATCH * sizeof(float);  // 1 MiB

  if (ws_size >= TBL_BYTES + XT_BYTES) {
    __half2* tbl = (__half2*)d_ws;
    float*   xT  = (float*)((char*)d_ws + TBL_BYTES);
    prep<<<dim3(NSUB / 2 + 64), dim3(256), 0, stream>>>(
        x, w0, b0, w1, b1, w2, b2, ss, rs, tbl, xT);
    mlp_tbl_lds<<<dim3(OUT_SZ * (BATCH / 512)), dim3(512), 0, stream>>>(
        xT, tbl, (float*)d_out);
  } else {
    mlp_raw<<<dim3(OUT_SZ * (BATCH / 256)), dim3(512), 0, stream>>>(
        x, w0, b0, w1, b1, w2, b2, ss, rs, (float*)d_out);
  }
}